// Round 2
// 345.340 us; speedup vs baseline: 1.0664x; 1.0664x over previous
//
#include <hip/hip_runtime.h>
#include <math.h>

// Fastfood layer, round 5: fully in-register FWHT (round-4 + compile fix:
// nontemporal builtins need native vector types, not HIP_vector_type).
//
// One wave per row, 16 elements per lane. FWHT-1024 stages, all in registers:
//   bits 0-3 : reg-index butterflies
//   bits 4-7 : lane bits 0-3 via DPP (xor1=quad_perm B1, xor2=4E,
//              xor4=half_mirror . quad_perm 1B, xor8=row_ror:8)
//   bit 8    : lane bit 4 via v_permlane16_swap pair trick (swap, +/-, swap)
//   bit 9    : lane bit 5 via v_permlane32_swap pair trick
// This removes BOTH LDS transpose round-trips of round 3; the only LDS
// traffic left is the staging required by the random permutation:
// 4x ds_write_b128 + 16 gather ds_read_b32 per m  (was 36 DS instrs, 3 RAW
// chains; now 20 DS instrs, 1 RAW chain).
//
// FWHT#1 runs in the natural layout (i = 16*lane + k).  The gather reads P/G
// at L2' positions (i' = 256*b + 4*lane + c), so its output lands directly in
// the L2' layout; since Hadamard stages commute, the same fwht_full routine
// (regs = bits {0,1,8,9}, lanes = bits 2-7) performs FWHT#2, and the epilogue
// keeps fully contiguous float4 loads/stores.
//
// LDS padding: addr(i) = i + 4*(i>>6) -- 16B-aligned groups, stride-16 b128
// writes at the 8-words/bank minimum (verified in round 3).

typedef unsigned uint2_ev __attribute__((ext_vector_type(2)));
typedef float    f32x4    __attribute__((ext_vector_type(4)));

template <int CTRL>
__device__ __forceinline__ float dpp_f(float x) {
    return __int_as_float(
        __builtin_amdgcn_mov_dpp(__float_as_int(x), CTRL, 0xF, 0xF, true));
}

#define DPP_XOR1 0xB1   // quad_perm [1,0,3,2]
#define DPP_XOR2 0x4E   // quad_perm [2,3,0,1]
#define DPP_XOR3 0x1B   // quad_perm [3,2,1,0]
#define DPP_HMIR 0x141  // row_half_mirror: lane ^ 7
#define DPP_ROR8 0x128  // row_ror:8 == lane ^ 8

// Full 10-stage FWHT-1024 with zero LDS traffic.
// Stage order is irrelevant (Hadamard stages over disjoint bits commute).
__device__ __forceinline__ void fwht_full(float v[16], float sg0, float sg1,
                                          float sg2, float sg3, float sg4,
                                          float sg5) {
    (void)sg4; (void)sg5;
    // reg-index bits (4 stages)
#pragma unroll
    for (int h = 1; h < 16; h <<= 1) {
#pragma unroll
        for (int k = 0; k < 16; ++k) {
            if (!(k & h)) {
                float a = v[k], b = v[k ^ h];
                v[k] = a + b;
                v[k ^ h] = a - b;
            }
        }
    }
    // lane bits 0-3 via DPP: new = partner + sg*v
#pragma unroll
    for (int k = 0; k < 16; ++k) v[k] = fmaf(v[k], sg0, dpp_f<DPP_XOR1>(v[k]));
#pragma unroll
    for (int k = 0; k < 16; ++k) v[k] = fmaf(v[k], sg1, dpp_f<DPP_XOR2>(v[k]));
#pragma unroll
    for (int k = 0; k < 16; ++k)
        v[k] = fmaf(v[k], sg2, dpp_f<DPP_XOR3>(dpp_f<DPP_HMIR>(v[k])));
#pragma unroll
    for (int k = 0; k < 16; ++k) v[k] = fmaf(v[k], sg3, dpp_f<DPP_ROR8>(v[k]));

    // lane bit 4 (partner = lane ^ 16): pair trick, 4 instrs / 2 elements.
    // swap(a,b) -> a'={a_row0,b_row0}, b'={a_row1,b_row1} per 32-lane half;
    // s=a'+b', d=a'-b'; swap(s,d) restores layout with butterflied values.
#if __has_builtin(__builtin_amdgcn_permlane16_swap)
#pragma unroll
    for (int p = 0; p < 8; ++p) {
        uint2_ev r = __builtin_amdgcn_permlane16_swap(
            __float_as_uint(v[2 * p]), __float_as_uint(v[2 * p + 1]), false,
            false);
        float s = __uint_as_float(r.x) + __uint_as_float(r.y);
        float d = __uint_as_float(r.x) - __uint_as_float(r.y);
        uint2_ev q = __builtin_amdgcn_permlane16_swap(
            __float_as_uint(s), __float_as_uint(d), false, false);
        v[2 * p]     = __uint_as_float(q.x);
        v[2 * p + 1] = __uint_as_float(q.y);
    }
#else
#pragma unroll
    for (int k = 0; k < 16; ++k) {
        float t = __int_as_float(
            __builtin_amdgcn_ds_swizzle(__float_as_int(v[k]), 0x401F));
        v[k] = fmaf(v[k], sg4, t);
    }
#endif

    // lane bit 5 (partner = lane ^ 32): same trick with 32-lane halves.
#if __has_builtin(__builtin_amdgcn_permlane32_swap)
#pragma unroll
    for (int p = 0; p < 8; ++p) {
        uint2_ev r = __builtin_amdgcn_permlane32_swap(
            __float_as_uint(v[2 * p]), __float_as_uint(v[2 * p + 1]), false,
            false);
        float s = __uint_as_float(r.x) + __uint_as_float(r.y);
        float d = __uint_as_float(r.x) - __uint_as_float(r.y);
        uint2_ev q = __builtin_amdgcn_permlane32_swap(
            __float_as_uint(s), __float_as_uint(d), false, false);
        v[2 * p]     = __uint_as_float(q.x);
        v[2 * p + 1] = __uint_as_float(q.y);
    }
#else
#pragma unroll
    for (int k = 0; k < 16; ++k) {
        float t = __shfl_xor(v[k], 32, 64);
        v[k] = fmaf(v[k], sg5, t);
    }
#endif
}

__global__ __launch_bounds__(256) void fastfood_kernel(
    const float* __restrict__ x, const float* __restrict__ B,
    const float* __restrict__ G, const float* __restrict__ S,
    const int* __restrict__ P, const float* __restrict__ u_rand,
    float* __restrict__ out)
{
    __shared__ float lds[4 * 1088];           // 4 waves * padded 1024
    const int lane = threadIdx.x & 63;
    const int wv   = threadIdx.x >> 6;
    const int row  = blockIdx.x * 4 + wv;

    const float sg0 = (lane & 1)  ? -1.f : 1.f;
    const float sg1 = (lane & 2)  ? -1.f : 1.f;
    const float sg2 = (lane & 4)  ? -1.f : 1.f;
    const float sg3 = (lane & 8)  ? -1.f : 1.f;
    const float sg4 = (lane & 16) ? -1.f : 1.f;
    const float sg5 = (lane & 32) ? -1.f : 1.f;

    float* wlds = lds + wv * 1088;
    // natural-layout padded write base: addr(16L+4j+c) = i + 4*(i>>6)
    float4* w4L1 = (float4*)(wlds + 16 * lane + 4 * (lane >> 2));

    const float c_arg = 0.03125f * 0.15915494309189535f;  // (1/32)*(1/2pi)
    const float c_amp = 0.015625f;                        // sqrt(2/8192)

    // Load x row once (natural layout, streamed -> nontemporal)
    float xv[16];
    {
        const f32x4* x4 =
            (const f32x4*)(x + (size_t)row * 1024 + 16 * lane);
#pragma unroll
        for (int j = 0; j < 4; ++j) {
            f32x4 t = __builtin_nontemporal_load(&x4[j]);
            xv[4 * j + 0] = t.x; xv[4 * j + 1] = t.y;
            xv[4 * j + 2] = t.z; xv[4 * j + 3] = t.w;
        }
    }

#pragma unroll 1
    for (int m = 0; m < 8; ++m) {
        const int mo = m * 1024;
        float v[16];

        // v = x * B[m]  (natural layout)
        {
            const float4* B4 = (const float4*)(B + mo + 16 * lane);
#pragma unroll
            for (int j = 0; j < 4; ++j) {
                float4 b = B4[j];
                v[4 * j + 0] = xv[4 * j + 0] * b.x;
                v[4 * j + 1] = xv[4 * j + 1] * b.y;
                v[4 * j + 2] = xv[4 * j + 2] * b.z;
                v[4 * j + 3] = xv[4 * j + 3] * b.w;
            }
        }

        // ---- FWHT #1, fully in registers ----
        fwht_full(v, sg0, sg1, sg2, sg3, sg4, sg5);

        // Issue P/G loads for the gather BEFORE the staging writes so their
        // latency overlaps the LDS round trip (they are independent).
        const int4*   P4 = (const int4*)(P + mo);
        const float4* G4 = (const float4*)(G + mo);
        int4   pj[4];
        float4 gj[4];
#pragma unroll
        for (int j = 0; j < 4; ++j) {
            pj[j] = P4[64 * j + lane];
            gj[j] = G4[64 * j + lane];
        }

        // Staging write for the gather (natural positions, 4x b128)
#pragma unroll
        for (int j = 0; j < 4; ++j)
            w4L1[j] = make_float4(v[4 * j + 0], v[4 * j + 1],
                                  v[4 * j + 2], v[4 * j + 3]);

        // Random gather at L2' positions (i' = 256j + 4*lane + c) * G.
        // Result lands directly in the L2' register layout:
        //   reg k = 4b + c  ->  i' bits {0,1} = c, bits {8,9} = b.
#pragma unroll
        for (int j = 0; j < 4; ++j) {
            int4 p = pj[j];
            float4 g = gj[j];
            v[4 * j + 0] = wlds[p.x + ((p.x >> 6) << 2)] * g.x;
            v[4 * j + 1] = wlds[p.y + ((p.y >> 6) << 2)] * g.y;
            v[4 * j + 2] = wlds[p.z + ((p.z >> 6) << 2)] * g.z;
            v[4 * j + 3] = wlds[p.w + ((p.w >> 6) << 2)] * g.w;
        }

        // ---- FWHT #2, fully in registers (L2' layout, stages commute) ----
        fwht_full(v, sg0, sg1, sg2, sg3, sg4, sg5);

        // Epilogue in L2': element i = b*256 + 4*lane + c -> float4 idx b*64+lane
        {
            const float4* S4 = (const float4*)(S + mo);
            const float4* U4 = (const float4*)(u_rand + mo);
            f32x4* o4 = (f32x4*)(out + (size_t)row * 8192 + mo);
#pragma unroll
            for (int b = 0; b < 4; ++b) {
                int idx = b * 64 + lane;
                float4 sv = S4[idx], uv = U4[idx];
                f32x4 rr;
                rr.x = __builtin_amdgcn_cosf(__builtin_amdgcn_fractf(
                           fmaf(v[4 * b + 0] * sv.x, c_arg, uv.x))) * c_amp;
                rr.y = __builtin_amdgcn_cosf(__builtin_amdgcn_fractf(
                           fmaf(v[4 * b + 1] * sv.y, c_arg, uv.y))) * c_amp;
                rr.z = __builtin_amdgcn_cosf(__builtin_amdgcn_fractf(
                           fmaf(v[4 * b + 2] * sv.z, c_arg, uv.z))) * c_amp;
                rr.w = __builtin_amdgcn_cosf(__builtin_amdgcn_fractf(
                           fmaf(v[4 * b + 3] * sv.w, c_arg, uv.w))) * c_amp;
                __builtin_nontemporal_store(rr, &o4[idx]);
            }
        }
    }
}

extern "C" void kernel_launch(void* const* d_in, const int* in_sizes, int n_in,
                              void* d_out, int out_size, void* d_ws, size_t ws_size,
                              hipStream_t stream) {
    const float* x = (const float*)d_in[0];
    const float* B = (const float*)d_in[1];
    const float* G = (const float*)d_in[2];
    const float* S = (const float*)d_in[3];
    const int*   P = (const int*)d_in[4];
    const float* u = (const float*)d_in[5];
    float* out = (float*)d_out;

    dim3 grid(2048), block(256);
    hipLaunchKernelGGL(fastfood_kernel, grid, block, 0, stream,
                       x, B, G, S, P, u, out);
}

// Round 3
// 335.651 us; speedup vs baseline: 1.0972x; 1.0289x over previous
//
#include <hip/hip_runtime.h>
#include <math.h>

// Fastfood layer, round 6: fully in-register FWHT + 2 rows per wave (ILP-2).
//
// Round-5 post-mortem: removing the LDS transposes gave only -6%, so the
// binding constraint is serial per-m chain latency (L2 table loads -> FWHT#1
// -> gather -> FWHT#2 -> epilogue) with a single dataflow per wave.  This
// round each wave processes TWO x-rows with ONE set of B/P/G/S/u table loads:
//   - two independent chains interleaved instruction-by-instruction (fwht2)
//     so one row's stalls are hidden under the other row's VALU work,
//   - L2 table traffic halved (tables loaded once per wave, reused), gather
//     pad-offsets computed once,
//   - grid 1024 blocks (4096 waves = 4/SIMD, matching VGPR-limited occupancy).
//
// FWHT-1024, all in registers (per row):
//   bits 0-3 : reg-index butterflies
//   bits 4-7 : lane bits 0-3 via DPP (xor1=B1, xor2=4E, xor4=HMIR.1B, xor8=ror8)
//   bit 8    : v_permlane16_swap pair trick (swap, +/-, swap)
//   bit 9    : v_permlane32_swap pair trick
// LDS only for the permutation staging: 4x ds_write_b128 + 16 ds_read_b32
// per row per m.  Padding addr(i) = i + 4*(i>>6) keeps b128 writes
// conflict-free; per-wave slices are private so no barriers are needed.

typedef unsigned uint2_ev __attribute__((ext_vector_type(2)));
typedef float    f32x4    __attribute__((ext_vector_type(4)));

template <int CTRL>
__device__ __forceinline__ float dpp_f(float x) {
    return __int_as_float(
        __builtin_amdgcn_mov_dpp(__float_as_int(x), CTRL, 0xF, 0xF, true));
}

#define DPP_XOR1 0xB1   // quad_perm [1,0,3,2]
#define DPP_XOR2 0x4E   // quad_perm [2,3,0,1]
#define DPP_XOR3 0x1B   // quad_perm [3,2,1,0]
#define DPP_HMIR 0x141  // row_half_mirror: lane ^ 7
#define DPP_ROR8 0x128  // row_ror:8 == lane ^ 8

// One permlane16_swap butterfly step on a register pair.
__device__ __forceinline__ void pl16_pair(float& e0, float& e1) {
    uint2_ev r = __builtin_amdgcn_permlane16_swap(
        __float_as_uint(e0), __float_as_uint(e1), false, false);
    float s = __uint_as_float(r.x) + __uint_as_float(r.y);
    float d = __uint_as_float(r.x) - __uint_as_float(r.y);
    uint2_ev q = __builtin_amdgcn_permlane16_swap(
        __float_as_uint(s), __float_as_uint(d), false, false);
    e0 = __uint_as_float(q.x);
    e1 = __uint_as_float(q.y);
}

__device__ __forceinline__ void pl32_pair(float& e0, float& e1) {
    uint2_ev r = __builtin_amdgcn_permlane32_swap(
        __float_as_uint(e0), __float_as_uint(e1), false, false);
    float s = __uint_as_float(r.x) + __uint_as_float(r.y);
    float d = __uint_as_float(r.x) - __uint_as_float(r.y);
    uint2_ev q = __builtin_amdgcn_permlane32_swap(
        __float_as_uint(s), __float_as_uint(d), false, false);
    e0 = __uint_as_float(q.x);
    e1 = __uint_as_float(q.y);
}

// Full 10-stage FWHT-1024 on TWO rows, interleaved for ILP.
__device__ __forceinline__ void fwht2(float a[16], float b[16], float sg0,
                                      float sg1, float sg2, float sg3) {
    // reg-index bits (4 stages)
#pragma unroll
    for (int h = 1; h < 16; h <<= 1) {
#pragma unroll
        for (int k = 0; k < 16; ++k) {
            if (!(k & h)) {
                float t0 = a[k], t1 = a[k ^ h];
                a[k] = t0 + t1;
                a[k ^ h] = t0 - t1;
                float u0 = b[k], u1 = b[k ^ h];
                b[k] = u0 + u1;
                b[k ^ h] = u0 - u1;
            }
        }
    }
    // lane bits 0-3 via DPP: new = partner + sg*v
#pragma unroll
    for (int k = 0; k < 16; ++k) {
        a[k] = fmaf(a[k], sg0, dpp_f<DPP_XOR1>(a[k]));
        b[k] = fmaf(b[k], sg0, dpp_f<DPP_XOR1>(b[k]));
    }
#pragma unroll
    for (int k = 0; k < 16; ++k) {
        a[k] = fmaf(a[k], sg1, dpp_f<DPP_XOR2>(a[k]));
        b[k] = fmaf(b[k], sg1, dpp_f<DPP_XOR2>(b[k]));
    }
#pragma unroll
    for (int k = 0; k < 16; ++k) {
        a[k] = fmaf(a[k], sg2, dpp_f<DPP_XOR3>(dpp_f<DPP_HMIR>(a[k])));
        b[k] = fmaf(b[k], sg2, dpp_f<DPP_XOR3>(dpp_f<DPP_HMIR>(b[k])));
    }
#pragma unroll
    for (int k = 0; k < 16; ++k) {
        a[k] = fmaf(a[k], sg3, dpp_f<DPP_ROR8>(a[k]));
        b[k] = fmaf(b[k], sg3, dpp_f<DPP_ROR8>(b[k]));
    }
    // lane bit 4 (lane ^ 16) and bit 5 (lane ^ 32): pair tricks
#pragma unroll
    for (int p = 0; p < 8; ++p) {
        pl16_pair(a[2 * p], a[2 * p + 1]);
        pl16_pair(b[2 * p], b[2 * p + 1]);
    }
#pragma unroll
    for (int p = 0; p < 8; ++p) {
        pl32_pair(a[2 * p], a[2 * p + 1]);
        pl32_pair(b[2 * p], b[2 * p + 1]);
    }
}

__global__ __launch_bounds__(256, 3) void fastfood_kernel(
    const float* __restrict__ x, const float* __restrict__ B,
    const float* __restrict__ G, const float* __restrict__ S,
    const int* __restrict__ P, const float* __restrict__ u_rand,
    float* __restrict__ out)
{
    __shared__ float lds[4 * 2176];           // 4 waves * 2 rows * padded 1024
    const int lane = threadIdx.x & 63;
    const int wv   = threadIdx.x >> 6;
    const int row  = blockIdx.x * 8 + wv * 2; // two consecutive rows per wave

    const float sg0 = (lane & 1) ? -1.f : 1.f;
    const float sg1 = (lane & 2) ? -1.f : 1.f;
    const float sg2 = (lane & 4) ? -1.f : 1.f;
    const float sg3 = (lane & 8) ? -1.f : 1.f;

    float* ldsA = lds + wv * 2176;
    float* ldsB = ldsA + 1088;
    // natural-layout padded write offset (all 16 of a lane's elements are
    // contiguous: pad only inserts at 64-element boundaries)
    const int woff = 16 * lane + 4 * (lane >> 2);
    float4* wA = (float4*)(ldsA + woff);
    float4* wB = (float4*)(ldsB + woff);

    const float c_arg = 0.03125f * 0.15915494309189535f;  // (1/32)*(1/2pi)
    const float c_amp = 0.015625f;                        // sqrt(2/8192)

    // Load both x rows once (natural layout, streamed -> nontemporal)
    float xvA[16], xvB[16];
    {
        const f32x4* xa = (const f32x4*)(x + (size_t)row * 1024 + 16 * lane);
        const f32x4* xb = (const f32x4*)(x + (size_t)(row + 1) * 1024 + 16 * lane);
#pragma unroll
        for (int j = 0; j < 4; ++j) {
            f32x4 t = __builtin_nontemporal_load(&xa[j]);
            xvA[4 * j + 0] = t.x; xvA[4 * j + 1] = t.y;
            xvA[4 * j + 2] = t.z; xvA[4 * j + 3] = t.w;
            f32x4 u = __builtin_nontemporal_load(&xb[j]);
            xvB[4 * j + 0] = u.x; xvB[4 * j + 1] = u.y;
            xvB[4 * j + 2] = u.z; xvB[4 * j + 3] = u.w;
        }
    }

#pragma unroll 1
    for (int m = 0; m < 8; ++m) {
        const int mo = m * 1024;
        float vA[16], vB[16];

        // v = x * B[m]  (natural layout; B loaded once, used for both rows)
        {
            const float4* B4 = (const float4*)(B + mo + 16 * lane);
#pragma unroll
            for (int j = 0; j < 4; ++j) {
                float4 bb = B4[j];
                vA[4 * j + 0] = xvA[4 * j + 0] * bb.x;
                vA[4 * j + 1] = xvA[4 * j + 1] * bb.y;
                vA[4 * j + 2] = xvA[4 * j + 2] * bb.z;
                vA[4 * j + 3] = xvA[4 * j + 3] * bb.w;
                vB[4 * j + 0] = xvB[4 * j + 0] * bb.x;
                vB[4 * j + 1] = xvB[4 * j + 1] * bb.y;
                vB[4 * j + 2] = xvB[4 * j + 2] * bb.z;
                vB[4 * j + 3] = xvB[4 * j + 3] * bb.w;
            }
        }

        // ---- FWHT #1, both rows, fully in registers ----
        fwht2(vA, vB, sg0, sg1, sg2, sg3);

        // P/G loads issued before the staging writes (independent; their
        // L2 latency overlaps the LDS round trip).  Loaded ONCE per wave.
        const int4*   P4 = (const int4*)(P + mo);
        const float4* G4 = (const float4*)(G + mo);
        int4   pj[4];
        float4 gj[4];
#pragma unroll
        for (int j = 0; j < 4; ++j) {
            pj[j] = P4[64 * j + lane];
            gj[j] = G4[64 * j + lane];
        }

        // Staging writes (natural positions, 4x b128 per row)
#pragma unroll
        for (int j = 0; j < 4; ++j) {
            wA[j] = make_float4(vA[4 * j + 0], vA[4 * j + 1],
                                vA[4 * j + 2], vA[4 * j + 3]);
            wB[j] = make_float4(vB[4 * j + 0], vB[4 * j + 1],
                                vB[4 * j + 2], vB[4 * j + 3]);
        }

        // Random gather at L2' positions (i' = 256j + 4*lane + c) * G.
        // Pad-offsets computed once, reused for both rows.
#pragma unroll
        for (int j = 0; j < 4; ++j) {
            int4 p = pj[j];
            float4 g = gj[j];
            int o0 = p.x + ((p.x >> 6) << 2);
            int o1 = p.y + ((p.y >> 6) << 2);
            int o2 = p.z + ((p.z >> 6) << 2);
            int o3 = p.w + ((p.w >> 6) << 2);
            vA[4 * j + 0] = ldsA[o0] * g.x;
            vA[4 * j + 1] = ldsA[o1] * g.y;
            vA[4 * j + 2] = ldsA[o2] * g.z;
            vA[4 * j + 3] = ldsA[o3] * g.w;
            vB[4 * j + 0] = ldsB[o0] * g.x;
            vB[4 * j + 1] = ldsB[o1] * g.y;
            vB[4 * j + 2] = ldsB[o2] * g.z;
            vB[4 * j + 3] = ldsB[o3] * g.w;
        }

        // ---- FWHT #2, both rows (L2' layout, stages commute) ----
        fwht2(vA, vB, sg0, sg1, sg2, sg3);

        // Epilogue in L2': element i = b*256 + 4*lane + c -> float4 idx b*64+lane
        // S/u loaded once, used for both rows.
        {
            const float4* S4 = (const float4*)(S + mo);
            const float4* U4 = (const float4*)(u_rand + mo);
            f32x4* oA = (f32x4*)(out + (size_t)row * 8192 + mo);
            f32x4* oB = (f32x4*)(out + (size_t)(row + 1) * 8192 + mo);
#pragma unroll
            for (int b = 0; b < 4; ++b) {
                int idx = b * 64 + lane;
                float4 sv = S4[idx], uv = U4[idx];
                f32x4 ra, rb;
                ra.x = __builtin_amdgcn_cosf(__builtin_amdgcn_fractf(
                           fmaf(vA[4 * b + 0] * sv.x, c_arg, uv.x))) * c_amp;
                ra.y = __builtin_amdgcn_cosf(__builtin_amdgcn_fractf(
                           fmaf(vA[4 * b + 1] * sv.y, c_arg, uv.y))) * c_amp;
                ra.z = __builtin_amdgcn_cosf(__builtin_amdgcn_fractf(
                           fmaf(vA[4 * b + 2] * sv.z, c_arg, uv.z))) * c_amp;
                ra.w = __builtin_amdgcn_cosf(__builtin_amdgcn_fractf(
                           fmaf(vA[4 * b + 3] * sv.w, c_arg, uv.w))) * c_amp;
                rb.x = __builtin_amdgcn_cosf(__builtin_amdgcn_fractf(
                           fmaf(vB[4 * b + 0] * sv.x, c_arg, uv.x))) * c_amp;
                rb.y = __builtin_amdgcn_cosf(__builtin_amdgcn_fractf(
                           fmaf(vB[4 * b + 1] * sv.y, c_arg, uv.y))) * c_amp;
                rb.z = __builtin_amdgcn_cosf(__builtin_amdgcn_fractf(
                           fmaf(vB[4 * b + 2] * sv.z, c_arg, uv.z))) * c_amp;
                rb.w = __builtin_amdgcn_cosf(__builtin_amdgcn_fractf(
                           fmaf(vB[4 * b + 3] * sv.w, c_arg, uv.w))) * c_amp;
                __builtin_nontemporal_store(ra, &oA[idx]);
                __builtin_nontemporal_store(rb, &oB[idx]);
            }
        }
    }
}

extern "C" void kernel_launch(void* const* d_in, const int* in_sizes, int n_in,
                              void* d_out, int out_size, void* d_ws, size_t ws_size,
                              hipStream_t stream) {
    const float* x = (const float*)d_in[0];
    const float* B = (const float*)d_in[1];
    const float* G = (const float*)d_in[2];
    const float* S = (const float*)d_in[3];
    const int*   P = (const int*)d_in[4];
    const float* u = (const float*)d_in[5];
    float* out = (float*)d_out;

    dim3 grid(1024), block(256);
    hipLaunchKernelGGL(fastfood_kernel, grid, block, 0, stream,
                       x, B, G, S, P, u, out);
}